// Round 2
// baseline (760.254 us; speedup 1.0000x reference)
//
#include <hip/hip_runtime.h>
#include <math.h>

// Problem: B=1048576 rows x C=128 classes, fp32 logits, int targets.
// out = mean(logsumexp(x) - x_t)  +  0.5 * mean_{t==1 & argmax==0}( -log1p(-1/s) )
// where s = sum exp(x - m); when argmax==0, p0 = 1/s exactly.
#define CLS 128
#define PEN_WEIGHT 0.5f

// ws layout: ws[0]=ce_sum, ws[1]=pen_sum, ws[2]=count (as float)
__global__ void zero_ws_kernel(float* ws) {
    if (threadIdx.x < 4) ws[threadIdx.x] = 0.0f;
}

// 16 lanes per row, TWO float4 per lane (gl*4 and 64+gl*4) = all 128 cols.
// Each wave handles 4 rows per iteration; block of 256 threads = 16 rows/iter,
// 256 rows per block over 16 iterations.
__global__ __launch_bounds__(256) void penalize_loss_main(
        const float* __restrict__ predicts,
        const int*   __restrict__ targets,
        float* __restrict__ ws, int B) {
    const int tid  = threadIdx.x;
    const int lane = tid & 63;
    const int wave = tid >> 6;        // 0..3
    const int gl   = lane & 15;       // lane within 16-lane row group

    float acc_ce = 0.0f, acc_pen = 0.0f, acc_cnt = 0.0f;

    const int r_block = blockIdx.x * 256;   // 256 rows per block
    for (int i = 0; i < 16; ++i) {
        const int r = r_block + i * 16 + wave * 4 + (lane >> 4);
        if (r < B) {
            const float* row = predicts + (size_t)r * CLS;
            const float4 v1 = *(const float4*)(row + gl * 4);        // cols 0..63
            const float4 v2 = *(const float4*)(row + 64 + gl * 4);   // cols 64..127
            const int t = targets[r];

            // row max over all 128 elements (8 local + 4-step butterfly in group)
            float lm = fmaxf(fmaxf(fmaxf(v1.x, v1.y), fmaxf(v1.z, v1.w)),
                             fmaxf(fmaxf(v2.x, v2.y), fmaxf(v2.z, v2.w)));
            lm = fmaxf(lm, __shfl_xor(lm, 1, 64));
            lm = fmaxf(lm, __shfl_xor(lm, 2, 64));
            lm = fmaxf(lm, __shfl_xor(lm, 4, 64));
            lm = fmaxf(lm, __shfl_xor(lm, 8, 64));

            // row sum of exp(x - m)
            float e = __expf(v1.x - lm) + __expf(v1.y - lm)
                    + __expf(v1.z - lm) + __expf(v1.w - lm)
                    + __expf(v2.x - lm) + __expf(v2.y - lm)
                    + __expf(v2.z - lm) + __expf(v2.w - lm);
            e += __shfl_xor(e, 1, 64);
            e += __shfl_xor(e, 2, 64);
            e += __shfl_xor(e, 4, 64);
            e += __shfl_xor(e, 8, 64);
            // e == s (uniform within the 16-lane group)

            // pred==0  <=>  x[0] == row max (argmax ties break to index 0).
            // x[0] lives in v1.x of the group's gl==0 lane; its ballot bit is
            // at position (lane & 48).
            const unsigned long long b = __ballot(v1.x == lm);
            const bool pred0 = (b >> (lane & 48)) & 1ull;

            if (gl == 0) {
                acc_ce += lm + __logf(e);           // logsumexp
                if (t == 1 && pred0) {
                    // argmax==0 => p0 = exp(x0-m)/s = 1/s exactly
                    acc_pen += -log1pf(-1.0f / e);
                    acc_cnt += 1.0f;
                }
            }
            // lane holding x_t subtracts it (no shuffle gather needed)
            if (gl == ((t >> 2) & 15)) {
                const int j = t & 3;
                float xt;
                if (t & 64) xt = (j == 0) ? v2.x : (j == 1) ? v2.y : (j == 2) ? v2.z : v2.w;
                else        xt = (j == 0) ? v1.x : (j == 1) ? v1.y : (j == 2) ? v1.z : v1.w;
                acc_ce -= xt;
            }
        }
    }

    // full-wave butterfly sum (64 lanes)
    for (int mask = 1; mask < 64; mask <<= 1) {
        acc_ce  += __shfl_xor(acc_ce,  mask, 64);
        acc_pen += __shfl_xor(acc_pen, mask, 64);
        acc_cnt += __shfl_xor(acc_cnt, mask, 64);
    }

    __shared__ float s_ce[4], s_pen[4], s_cnt[4];
    if (lane == 0) { s_ce[wave] = acc_ce; s_pen[wave] = acc_pen; s_cnt[wave] = acc_cnt; }
    __syncthreads();
    if (tid == 0) {
        atomicAdd(&ws[0], s_ce[0] + s_ce[1] + s_ce[2] + s_ce[3]);
        atomicAdd(&ws[1], s_pen[0] + s_pen[1] + s_pen[2] + s_pen[3]);
        atomicAdd(&ws[2], s_cnt[0] + s_cnt[1] + s_cnt[2] + s_cnt[3]);
    }
}

__global__ void finalize_kernel(const float* __restrict__ ws,
                                float* __restrict__ out, int B) {
    const float ce  = ws[0] / (float)B;
    const float pen = (ws[2] > 0.0f) ? (ws[1] / ws[2]) : 0.0f;
    out[0] = ce + PEN_WEIGHT * pen;
}

extern "C" void kernel_launch(void* const* d_in, const int* in_sizes, int n_in,
                              void* d_out, int out_size, void* d_ws, size_t ws_size,
                              hipStream_t stream) {
    const float* predicts = (const float*)d_in[0];
    const int*   targets  = (const int*)d_in[1];
    const int B = in_sizes[1];                    // 1048576
    float* ws  = (float*)d_ws;
    float* out = (float*)d_out;

    zero_ws_kernel<<<1, 64, 0, stream>>>(ws);
    const int nb = (B + 255) / 256;               // 4096 blocks, 256 rows each
    penalize_loss_main<<<nb, 256, 0, stream>>>(predicts, targets, ws, B);
    finalize_kernel<<<1, 1, 0, stream>>>(ws, out, B);
}

// Round 3
// 685.817 us; speedup vs baseline: 1.1085x; 1.1085x over previous
//
#include <hip/hip_runtime.h>
#include <math.h>

// Problem: B=1048576 rows x C=128 classes, fp32 logits, int targets.
// out = mean(logsumexp(x) - x_t)  +  0.5 * mean_{t==1 & argmax==0}( -log1p(-1/s) )
// where s = sum exp(x - m); when argmax==0, p0 = 1/s exactly.
#define CLS 128
#define PEN_WEIGHT 0.5f
#define ROWS_PER_BLOCK 256

// 16 lanes per row, TWO float4 per lane (cols gl*4 and 64+gl*4) = all 128 cols.
// Wave handles 4 rows/iter; 256-thread block = 16 rows/iter, 256 rows total.
// Each block writes 3 partials to distinct ws slots — NO atomics, NO zero-init.
__global__ __launch_bounds__(256) void penalize_loss_main(
        const float* __restrict__ predicts,
        const int*   __restrict__ targets,
        float* __restrict__ ws, int B, int nb) {
    const int tid  = threadIdx.x;
    const int lane = tid & 63;
    const int wave = tid >> 6;        // 0..3
    const int gl   = lane & 15;       // lane within 16-lane row group

    float acc_ce = 0.0f, acc_pen = 0.0f, acc_cnt = 0.0f;

    const int r_block = blockIdx.x * ROWS_PER_BLOCK;
    for (int i = 0; i < 16; ++i) {
        const int r = r_block + i * 16 + wave * 4 + (lane >> 4);
        if (r < B) {
            const float* row = predicts + (size_t)r * CLS;
            const float4 v1 = *(const float4*)(row + gl * 4);        // cols 0..63
            const float4 v2 = *(const float4*)(row + 64 + gl * 4);   // cols 64..127
            const int t = targets[r];

            // row max over 128 elements (8 local + 4-step butterfly in group)
            float lm = fmaxf(fmaxf(fmaxf(v1.x, v1.y), fmaxf(v1.z, v1.w)),
                             fmaxf(fmaxf(v2.x, v2.y), fmaxf(v2.z, v2.w)));
            lm = fmaxf(lm, __shfl_xor(lm, 1, 64));
            lm = fmaxf(lm, __shfl_xor(lm, 2, 64));
            lm = fmaxf(lm, __shfl_xor(lm, 4, 64));
            lm = fmaxf(lm, __shfl_xor(lm, 8, 64));

            // row sum of exp(x - m)
            float e = __expf(v1.x - lm) + __expf(v1.y - lm)
                    + __expf(v1.z - lm) + __expf(v1.w - lm)
                    + __expf(v2.x - lm) + __expf(v2.y - lm)
                    + __expf(v2.z - lm) + __expf(v2.w - lm);
            e += __shfl_xor(e, 1, 64);
            e += __shfl_xor(e, 2, 64);
            e += __shfl_xor(e, 4, 64);
            e += __shfl_xor(e, 8, 64);
            // e == s (uniform within the 16-lane group)

            // pred==0  <=>  x[0] == row max (argmax ties break to index 0).
            // x[0] is v1.x of the group's gl==0 lane; ballot bit at (lane&48).
            const unsigned long long b = __ballot(v1.x == lm);
            const bool pred0 = (b >> (lane & 48)) & 1ull;

            if (gl == 0) {
                acc_ce += lm + __logf(e);           // logsumexp
                if (t == 1 && pred0) {
                    // argmax==0 => p0 = exp(x0-m)/s = 1/s exactly
                    acc_pen += -log1pf(-1.0f / e);
                    acc_cnt += 1.0f;
                }
            }
            // lane holding x_t subtracts it (no shuffle gather needed)
            if (gl == ((t >> 2) & 15)) {
                const int j = t & 3;
                float xt;
                if (t & 64) xt = (j == 0) ? v2.x : (j == 1) ? v2.y : (j == 2) ? v2.z : v2.w;
                else        xt = (j == 0) ? v1.x : (j == 1) ? v1.y : (j == 2) ? v1.z : v1.w;
                acc_ce -= xt;
            }
        }
    }

    // full-wave butterfly sum (64 lanes)
    for (int mask = 1; mask < 64; mask <<= 1) {
        acc_ce  += __shfl_xor(acc_ce,  mask, 64);
        acc_pen += __shfl_xor(acc_pen, mask, 64);
        acc_cnt += __shfl_xor(acc_cnt, mask, 64);
    }

    __shared__ float s_ce[4], s_pen[4], s_cnt[4];
    if (lane == 0) { s_ce[wave] = acc_ce; s_pen[wave] = acc_pen; s_cnt[wave] = acc_cnt; }
    __syncthreads();
    if (tid == 0) {
        ws[blockIdx.x]          = s_ce[0]  + s_ce[1]  + s_ce[2]  + s_ce[3];
        ws[nb + blockIdx.x]     = s_pen[0] + s_pen[1] + s_pen[2] + s_pen[3];
        ws[2 * nb + blockIdx.x] = s_cnt[0] + s_cnt[1] + s_cnt[2] + s_cnt[3];
    }
}

// One block reduces the 3*nb partials and writes the scalar.
__global__ __launch_bounds__(256) void finalize_kernel(
        const float* __restrict__ ws, float* __restrict__ out, int B, int nb) {
    const int tid  = threadIdx.x;
    const int lane = tid & 63;
    const int wave = tid >> 6;

    float ce = 0.0f, pen = 0.0f, cnt = 0.0f;
    for (int i = tid; i < nb; i += 256) {
        ce  += ws[i];
        pen += ws[nb + i];
        cnt += ws[2 * nb + i];
    }
    for (int mask = 1; mask < 64; mask <<= 1) {
        ce  += __shfl_xor(ce,  mask, 64);
        pen += __shfl_xor(pen, mask, 64);
        cnt += __shfl_xor(cnt, mask, 64);
    }
    __shared__ float s_ce[4], s_pen[4], s_cnt[4];
    if (lane == 0) { s_ce[wave] = ce; s_pen[wave] = pen; s_cnt[wave] = cnt; }
    __syncthreads();
    if (tid == 0) {
        const float tce  = s_ce[0]  + s_ce[1]  + s_ce[2]  + s_ce[3];
        const float tpen = s_pen[0] + s_pen[1] + s_pen[2] + s_pen[3];
        const float tcnt = s_cnt[0] + s_cnt[1] + s_cnt[2] + s_cnt[3];
        const float mean_ce  = tce / (float)B;
        const float mean_pen = (tcnt > 0.0f) ? (tpen / tcnt) : 0.0f;
        out[0] = mean_ce + PEN_WEIGHT * mean_pen;
    }
}

extern "C" void kernel_launch(void* const* d_in, const int* in_sizes, int n_in,
                              void* d_out, int out_size, void* d_ws, size_t ws_size,
                              hipStream_t stream) {
    const float* predicts = (const float*)d_in[0];
    const int*   targets  = (const int*)d_in[1];
    const int B = in_sizes[1];                    // 1048576
    float* ws  = (float*)d_ws;
    float* out = (float*)d_out;

    const int nb = (B + ROWS_PER_BLOCK - 1) / ROWS_PER_BLOCK;   // 4096
    penalize_loss_main<<<nb, 256, 0, stream>>>(predicts, targets, ws, B, nb);
    finalize_kernel<<<1, 256, 0, stream>>>(ws, out, B, nb);
}